// Round 2
// baseline (961.634 us; speedup 1.0000x reference)
//
#include <hip/hip_runtime.h>
#include <math.h>

#define Bb 64
#define Dd 128
#define Tt 1024
#define Kk 2048
#define Nn 65536
#define DT 131072  // Dd*Tt

// ws layout (bytes):
//   cbT    @ 0        : float[128*2048] = 1048576
//   e2f    @ 1048576  : float[2048]     = 8192
//   Arow   @ 1056768  : float[65536]    = 262144
//   idxbuf @ 1318912  : int[65536]      = 262144
//   counts @ 1581056  : int[2048]       = 8192
//   part   @ 1589248  : double[4096]    = 32768
// total ~1.62 MB

// Transpose codebook (K,D)->(D,K) for coalesced LDS staging; zero histogram.
__global__ __launch_bounds__(256)
void prep_kernel(const float* __restrict__ cb, float* __restrict__ cbT,
                 int* __restrict__ counts) {
  int g = blockIdx.x * 256 + threadIdx.x;   // 1024 blocks -> 262144 elems
  int k = g >> 7, d = g & 127;
  cbT[d * Kk + k] = cb[g];
  if (g < Kk) counts[g] = 0;
}

// ||x||^2 per row, replicating numpy fp32 pairwise sum (n=128: 8 accumulators,
// sequential i, combine ((r0+r1)+(r2+r3))+((r4+r5)+(r6+r7))). __f*_rn blocks
// FMA contraction so each square is rounded like numpy's flat*flat.
__global__ __launch_bounds__(256)
void rowsum_kernel(const float* __restrict__ z, float* __restrict__ Arow) {
  const int g = blockIdx.x * 256 + threadIdx.x;   // 256 blocks -> 65536 rows
  const int b = g >> 10, t = g & 1023;
  const float* p = z + (size_t)b * DT + t;        // x_d = p[d*Tt]
  float r[8];
  #pragma unroll
  for (int j = 0; j < 8; ++j) {
    const float v = p[j * Tt];
    r[j] = __fmul_rn(v, v);
  }
  for (int i = 1; i < 16; ++i) {
    #pragma unroll
    for (int j = 0; j < 8; ++j) {
      const float v = p[(8 * i + j) * Tt];
      r[j] = __fadd_rn(r[j], __fmul_rn(v, v));
    }
  }
  Arow[g] = __fadd_rn(__fadd_rn(__fadd_rn(r[0], r[1]), __fadd_rn(r[2], r[3])),
                      __fadd_rn(__fadd_rn(r[4], r[5]), __fadd_rn(r[6], r[7])));
}

// ||e||^2 per code, same numpy fp32 pairwise order.
__global__ __launch_bounds__(256)
void e2f_kernel(const float* __restrict__ cb, float* __restrict__ e2f) {
  const int k = blockIdx.x * 256 + threadIdx.x;   // 8 blocks -> 2048 codes
  const float* p = cb + (size_t)k * Dd;
  float r[8];
  #pragma unroll
  for (int j = 0; j < 8; ++j) r[j] = __fmul_rn(p[j], p[j]);
  for (int i = 1; i < 16; ++i) {
    #pragma unroll
    for (int j = 0; j < 8; ++j) {
      const float v = p[8 * i + j];
      r[j] = __fadd_rn(r[j], __fmul_rn(v, v));
    }
  }
  e2f[k] = __fadd_rn(__fadd_rn(__fadd_rn(r[0], r[1]), __fadd_rn(r[2], r[3])),
                     __fadd_rn(__fadd_rn(r[4], r[5]), __fadd_rn(r[6], r[7])));
}

// Argmin replicating the np fp32 pipeline: M = x.e in f64 (error << 1 ulp of
// the BLAS fp32 result), then D = fl32(fl32(A - 2*fl32(M)) + e2) quantized
// exactly as numpy's (A - 2*M) + e2 elementwise fp32 ops; lowest-index ties.
// 64 rows/block, codes in 32 chunks of 64, 4x4 f64 micro-tile per thread.
__global__ __launch_bounds__(256, 2)
void argmin_kernel(const float* __restrict__ z, const float* __restrict__ cbT,
                   const float* __restrict__ e2f, const float* __restrict__ Arow,
                   int* __restrict__ idxbuf, int* __restrict__ counts,
                   float* __restrict__ out_idx) {
  __shared__ float zs[128][64];   // zs[d][row]   32 KB
  __shared__ float es[128][64];   // es[d][code]  32 KB (reused as reduce scratch)
  const int tid = threadIdx.x;
  const int n0 = blockIdx.x * 64;       // 1024 blocks
  const int b = n0 >> 10;
  const int t0 = n0 & 1023;
  const float* zb = z + (size_t)b * DT + t0;  // z[b,d,t0+i] = zb[d*Tt + i]
  {
    const int i = tid & 63;
    const int dg = tid >> 6;
    #pragma unroll
    for (int j = 0; j < 32; ++j) {
      int d = dg + 4 * j;
      zs[d][i] = zb[d * Tt + i];      // coalesced read, stride-1 LDS write
    }
  }
  const int rg = tid >> 4;   // row group 0..15 -> rows 4rg..4rg+3
  const int cg = tid & 15;   // code group 0..15 -> codes 4cg..4cg+3 (per chunk)
  float Ar[4];
  #pragma unroll
  for (int r = 0; r < 4; ++r) Ar[r] = Arow[n0 + rg * 4 + r];
  float best[4];
  int bidx[4];
  #pragma unroll
  for (int r = 0; r < 4; ++r) { best[r] = 1e30f; bidx[r] = 0; }

  for (int ch = 0; ch < 32; ++ch) {
    __syncthreads();   // protect es (and first-iter zs) before restaging
    {
      const int c = tid & 63;
      const int dg = tid >> 6;
      const float* p = cbT + ch * 64 + c;
      #pragma unroll
      for (int j = 0; j < 32; ++j) {
        int d = dg + 4 * j;
        es[d][c] = p[d * Kk];         // coalesced read, stride-1 LDS write
      }
    }
    __syncthreads();
    double acc[4][4];
    #pragma unroll
    for (int r = 0; r < 4; ++r)
      #pragma unroll
      for (int c = 0; c < 4; ++c) acc[r][c] = 0.0;
    #pragma unroll 4
    for (int d = 0; d < 128; ++d) {
      const float4 av = *(const float4*)&zs[d][rg * 4];
      const float4 bv = *(const float4*)&es[d][cg * 4];
      const double a0 = av.x, a1 = av.y, a2 = av.z, a3 = av.w;
      const double b0 = bv.x, b1 = bv.y, b2 = bv.z, b3 = bv.w;
      acc[0][0] += a0 * b0; acc[0][1] += a0 * b1; acc[0][2] += a0 * b2; acc[0][3] += a0 * b3;
      acc[1][0] += a1 * b0; acc[1][1] += a1 * b1; acc[1][2] += a1 * b2; acc[1][3] += a1 * b3;
      acc[2][0] += a2 * b0; acc[2][1] += a2 * b1; acc[2][2] += a2 * b2; acc[2][3] += a2 * b3;
      acc[3][0] += a3 * b0; acc[3][1] += a3 * b1; acc[3][2] += a3 * b2; acc[3][3] += a3 * b3;
    }
    const int kb = ch * 64 + cg * 4;
    #pragma unroll
    for (int c = 0; c < 4; ++c) {     // ascending k => strict '<' keeps lowest idx
      const float ef = e2f[kb + c];
      #pragma unroll
      for (int r = 0; r < 4; ++r) {
        const float m32 = (float)acc[r][c];                       // fl32(M)
        const float X = __fsub_rn(Ar[r], __fmul_rn(2.0f, m32));   // fl32(A - 2M)
        const float Dq = __fadd_rn(X, ef);                        // fl32(.. + e2)
        if (Dq < best[r]) { best[r] = Dq; bidx[r] = kb + c; }
      }
    }
  }
  __syncthreads();
  // cross-thread reduce per row (16 partials/row), reusing es as scratch
  float* sred = (float*)&es[0][0];          // 1024 floats = 4 KB
  int* ired = (int*)(sred + 1024);          // 4 KB
  #pragma unroll
  for (int r = 0; r < 4; ++r) {
    sred[(rg * 4 + r) * 16 + cg] = best[r];
    ired[(rg * 4 + r) * 16 + cg] = bidx[r];
  }
  __syncthreads();
  if (tid < 64) {
    float bs = sred[tid * 16];
    int bk = ired[tid * 16];
    for (int j = 1; j < 16; ++j) {
      float s = sred[tid * 16 + j];
      int k2 = ired[tid * 16 + j];
      if (s < bs || (s == bs && k2 < bk)) { bs = s; bk = k2; }
    }
    idxbuf[n0 + tid] = bk;
    out_idx[n0 + tid] = (float)bk;
    atomicAdd(&counts[bk], 1);
  }
}

// Gather z_q into (B,D,T) layout + f64 loss partials.
__global__ __launch_bounds__(256)
void gather_kernel(const float* __restrict__ z, const float* __restrict__ cb,
                   const int* __restrict__ idxbuf, float* __restrict__ out0,
                   double* __restrict__ part) {
  const int tid = threadIdx.x;
  const size_t o0 = ((size_t)blockIdx.x * 256 + tid) * 8;  // 4096 blocks
  const int b = (int)(o0 >> 17);
  const int dt = (int)(o0 & (size_t)(DT - 1));
  const int d = dt >> 10;
  const int t = dt & 1023;
  const int n = (b << 10) + t;
  const float4 z0 = *(const float4*)(z + o0);
  const float4 z1 = *(const float4*)(z + o0 + 4);
  float q[8];
  #pragma unroll
  for (int j = 0; j < 8; ++j) q[j] = cb[(size_t)idxbuf[n + j] * Dd + d];
  *(float4*)(out0 + o0)     = make_float4(q[0], q[1], q[2], q[3]);
  *(float4*)(out0 + o0 + 4) = make_float4(q[4], q[5], q[6], q[7]);
  const float zz[8] = {z0.x, z0.y, z0.z, z0.w, z1.x, z1.y, z1.z, z1.w};
  double s = 0.0;
  #pragma unroll
  for (int j = 0; j < 8; ++j) {
    const double dif = (double)zz[j] - (double)q[j];
    s += dif * dif;
  }
  #pragma unroll
  for (int o = 32; o > 0; o >>= 1) s += __shfl_down(s, o, 64);
  __shared__ double w4[4];
  if ((tid & 63) == 0) w4[tid >> 6] = s;
  __syncthreads();
  if (tid == 0) part[blockIdx.x] = w4[0] + w4[1] + w4[2] + w4[3];
}

__global__ __launch_bounds__(256)
void finalize_kernel(const int* __restrict__ counts, const double* __restrict__ part,
                     float* __restrict__ out) {
  const int tid = threadIdx.x;
  __shared__ double red[256];
  double s = 0.0;
  for (int i = tid; i < 4096; i += 256) s += part[i];
  red[tid] = s;
  __syncthreads();
  for (int o = 128; o > 0; o >>= 1) {
    if (tid < o) red[tid] += red[tid + o];
    __syncthreads();
  }
  const double loss = red[0];
  __syncthreads();
  double e = 0.0;
  for (int k = tid; k < 2048; k += 256) {
    const double p = (double)counts[k] / 65536.0;
    e += p * log(p + 1e-10);
  }
  red[tid] = e;
  __syncthreads();
  for (int o = 128; o > 0; o >>= 1) {
    if (tid < o) red[tid] += red[tid + o];
    __syncthreads();
  }
  if (tid == 0) {
    out[8388608] = (float)(0.25 * loss / 8388608.0);
    out[8388609] = (float)exp(-red[0]);
  }
}

extern "C" void kernel_launch(void* const* d_in, const int* in_sizes, int n_in,
                              void* d_out, int out_size, void* d_ws, size_t ws_size,
                              hipStream_t stream) {
  const float* z = (const float*)d_in[0];      // (B, D, T) fp32
  const float* cb = (const float*)d_in[1];     // (K, D) fp32
  float* out = (float*)d_out;                  // [z_q (8388608) | loss | perp | idx (65536)]
  char* ws = (char*)d_ws;
  float* cbT    = (float*)ws;
  float* e2f    = (float*)(ws + 1048576);
  float* Arow   = (float*)(ws + 1056768);
  int* idxbuf   = (int*)(ws + 1318912);
  int* counts   = (int*)(ws + 1581056);
  double* part  = (double*)(ws + 1589248);

  hipLaunchKernelGGL(prep_kernel,   dim3(1024), dim3(256), 0, stream, cb, cbT, counts);
  hipLaunchKernelGGL(rowsum_kernel, dim3(256),  dim3(256), 0, stream, z, Arow);
  hipLaunchKernelGGL(e2f_kernel,    dim3(8),    dim3(256), 0, stream, cb, e2f);
  hipLaunchKernelGGL(argmin_kernel, dim3(1024), dim3(256), 0, stream, z, cbT, e2f, Arow,
                     idxbuf, counts, out + 8388610);
  hipLaunchKernelGGL(gather_kernel, dim3(4096), dim3(256), 0, stream, z, cb, idxbuf, out, part);
  hipLaunchKernelGGL(finalize_kernel, dim3(1), dim3(256), 0, stream, counts, part, out);
}